// Round 8
// baseline (95.965 us; speedup 1.0000x reference)
//
#include <hip/hip_runtime.h>
#include <hip/hip_bf16.h>
#include <stdint.h>

// Shapes (fixed): S=4, B=2, F=64, P=16, T=32, H=64, W=64, HID=32
#define THW   131072   // 32*64*64
#define NS    4
#define NB    2
#define NF    64
#define NP    16
#define HID   32
#define BN_EPS 1e-5f
#define PXT   128      // pixels per block tile (4 waves x 32-px MFMA tiles)

typedef short  bf16x8  __attribute__((ext_vector_type(8)));
typedef float  f32x16  __attribute__((ext_vector_type(16)));

union FragU { uint32_t u[4]; bf16x8 v; uint4 q; };

__device__ __forceinline__ uint32_t pk2(float a, float b) {
    __hip_bfloat162 h = __float22bfloat162_rn(make_float2(a, b));
    uint32_t r;
    __builtin_memcpy(&r, &h, sizeof(r));
    return r;
}
__device__ __forceinline__ float lo16(uint32_t u) { return __builtin_bit_cast(float, u << 16); }
__device__ __forceinline__ float hi16(uint32_t u) { return __builtin_bit_cast(float, u & 0xFFFF0000u); }

// async global->LDS, 16B/lane: wave writes lds_base + lane*16 (1KB contiguous),
// reads per-lane gsrc (must be 16B-stride-coherent with lane).
__device__ __forceinline__ void glds16(const float* g, void* l) {
    __builtin_amdgcn_global_load_lds(
        (const __attribute__((address_space(1))) uint32_t*)g,
        (__attribute__((address_space(3))) uint32_t*)l, 16, 0, 0);
}

// Block = 256 threads = 4 waves = 128 contiguous pixels; wave wv owns px wv*32..+31.
// 2-phase LDS double-buffer over s (guide T3 minimum recipe):
//   STAGE(s+1) -> consume(s) -> vmcnt(0)+"memory" -> s_barrier
// (256,2): proven spill-free; LDS 79.6KB -> exactly 2 blocks/CU.
__global__ __launch_bounds__(256, 2) void gssm_kernel(
    const float* __restrict__ feats, const float* __restrict__ ps,
    const float* __restrict__ w1,    const float* __restrict__ gamma,
    const float* __restrict__ beta,  const float* __restrict__ mean,
    const float* __restrict__ var,   const float* __restrict__ w2,
    float* __restrict__ out)
{
    __shared__ __align__(16) float    fbuf[2][NF][PXT];   // 65536 B
    __shared__ __align__(16) float    pbuf[NP][PXT];      //  8192 B
    __shared__ __align__(16) uint32_t w1lds[32 * 44];     //  5632 B
    __shared__ float2 tbl[HID];                           //   256 B

    const int tid  = threadIdx.x;
    const int lane = tid & 63;
    const int wv   = tid >> 6;
    const int hi   = lane >> 5;
    const int ln   = lane & 31;

    // ---- stage w1 (BN-scale folded, bf16-packed) + tbl
    for (int t = tid; t < 1280; t += 256) {
        float2 v = ((const float2*)w1)[t];
        int o = t / 40, cp = t - o * 40;
        float sc = gamma[o] * rsqrtf(var[o] + BN_EPS);
        w1lds[o * 44 + (cp >> 3) * 8 + (cp & 7)] = pk2(v.x * sc, v.y * sc);
    }
    if (tid < HID) {
        float sc = gamma[tid] * rsqrtf(var[tid] + BN_EPS);
        tbl[tid] = make_float2(beta[tid] - mean[tid] * sc, w2[tid]);
    }

    const int px0g = blockIdx.x * PXT;        // global pixel (incl. b)
    const int b    = px0g >> 17;              // THW = 2^17
    const int px0  = px0g & (THW - 1);

    const float* featsb = feats + (long)b * NF * THW + px0;
    const float* psb    = ps    + (long)b * NP * THW + px0;
    const long   sstr   = (long)NB * NF * THW;

    // per-lane src offset within a plane-PAIR: lanes 0-31 -> plane f, px 4*ln..;
    // lanes 32-63 -> plane f+1. Matches LDS dest base+lane*16 over [f][128],[f+1][128].
    const long pl_off = (long)(lane >> 5) * THW + (ln << 2);
    const int  f0     = wv * 16;              // wave stages planes f0..f0+15 (8 instrs)

    auto stage_feats = [&](int s, int buf) {
        const float* base = featsb + (long)s * sstr;
        #pragma unroll
        for (int i = 0; i < 8; ++i) {
            int f = f0 + i * 2;
            glds16(base + (long)f * THW + pl_off, (void*)&fbuf[buf][f][0]);
        }
    };

    // ---- prologue: stage p (16 planes = 8 instrs, 2/wave) + feats(s=0)
    {
        #pragma unroll
        for (int i = 0; i < 2; ++i) {
            int p = wv * 4 + i * 2;
            glds16(psb + (long)p * THW + pl_off, (void*)&pbuf[p][0]);
        }
    }
    stage_feats(0, 0);
    asm volatile("s_waitcnt vmcnt(0) lgkmcnt(0)" ::: "memory");
    __builtin_amdgcn_s_barrier();

    // ---- hoist A fragments (w1*scale) and shift/w2
    FragU afr[5];
    {
        const uint32_t abase = (uint32_t)(ln * 44 + hi * 4);
        #pragma unroll
        for (int k = 0; k < 5; ++k)
            afr[k].q = *((const uint4*)&w1lds[abase + k * 8]);
    }
    float sh[16], wo[16];
    #pragma unroll
    for (int r = 0; r < 16; ++r) {
        float2 t = tbl[(r & 3) + 8 * (r >> 2) + 4 * hi];
        sh[r] = t.x;
        wo[r] = t.y;
    }

    const int pxloc = wv * 32 + ln;           // this lane's pixel within the block tile

    // ---- p fragment from pbuf (once)
    FragU bp;
    #pragma unroll
    for (int r = 0; r < 4; ++r)
        bp.u[r] = pk2(pbuf[hi * 8 + 2 * r][pxloc], pbuf[hi * 8 + 2 * r + 1][pxloc]);

    auto consume = [&](int buf, FragU* pk) -> float {
        #pragma unroll
        for (int kb = 0; kb < 4; ++kb)
            #pragma unroll
            for (int r = 0; r < 4; ++r)
                pk[kb].u[r] = pk2(fbuf[buf][kb * 16 + hi * 8 + 2 * r][pxloc],
                                  fbuf[buf][kb * 16 + hi * 8 + 2 * r + 1][pxloc]);
        f32x16 acc;
        #pragma unroll
        for (int r = 0; r < 16; ++r) acc[r] = 0.f;
        acc = __builtin_amdgcn_mfma_f32_32x32x16_bf16(afr[4].v, bp.v,    acc, 0, 0, 0);
        acc = __builtin_amdgcn_mfma_f32_32x32x16_bf16(afr[0].v, pk[0].v, acc, 0, 0, 0);
        acc = __builtin_amdgcn_mfma_f32_32x32x16_bf16(afr[1].v, pk[1].v, acc, 0, 0, 0);
        acc = __builtin_amdgcn_mfma_f32_32x32x16_bf16(afr[2].v, pk[2].v, acc, 0, 0, 0);
        acc = __builtin_amdgcn_mfma_f32_32x32x16_bf16(afr[3].v, pk[3].v, acc, 0, 0, 0);
        float pp[4] = {0.f, 0.f, 0.f, 0.f};
        #pragma unroll
        for (int r = 0; r < 16; ++r) {
            float h = fmaxf(acc[r] + sh[r], 0.f);
            pp[r & 3] = fmaf(h, wo[r], pp[r & 3]);
        }
        float part = (pp[0] + pp[1]) + (pp[2] + pp[3]);
        return part + __shfl_xor(part, 32);
    };

    FragU pk0[4], pk1[4], pk2f[4], pk3[4];
    float lg0, lg1, lg2, lg3;

    stage_feats(1, 1);                 // in flight during consume(0)
    lg0 = consume(0, pk0);
    asm volatile("s_waitcnt vmcnt(0)" ::: "memory");
    __builtin_amdgcn_s_barrier();

    stage_feats(2, 0);
    lg1 = consume(1, pk1);
    asm volatile("s_waitcnt vmcnt(0)" ::: "memory");
    __builtin_amdgcn_s_barrier();

    stage_feats(3, 1);
    lg2 = consume(0, pk2f);
    asm volatile("s_waitcnt vmcnt(0)" ::: "memory");
    __builtin_amdgcn_s_barrier();

    lg3 = consume(1, pk3);

    // ---- softmax over 4 logits (b2 shift-invariant: skipped)
    const float m   = fmaxf(fmaxf(lg0, lg1), fmaxf(lg2, lg3));
    const float e0  = __expf(lg0 - m), e1 = __expf(lg1 - m);
    const float e2  = __expf(lg2 - m), e3 = __expf(lg3 - m);
    const float inv = 1.f / (e0 + e1 + e2 + e3);
    const float a0 = e0 * inv, a1 = e1 * inv, a2 = e2 * inv, a3 = e3 * inv;

    const int thw = px0 + pxloc;

    // ---- out[b][f][thw] = sum_s alpha_s * feats_s (from bf16 frags), f = k*16+hi*8+j
    float* ob = out + ((long)(b * NF + hi * 8)) * THW + thw;
    #pragma unroll
    for (int k = 0; k < 4; ++k)
        #pragma unroll
        for (int r = 0; r < 4; ++r) {
            float vlo = a0 * lo16(pk0[k].u[r]);
            float vhi = a0 * hi16(pk0[k].u[r]);
            vlo = fmaf(a1, lo16(pk1[k].u[r]), vlo);
            vhi = fmaf(a1, hi16(pk1[k].u[r]), vhi);
            vlo = fmaf(a2, lo16(pk2f[k].u[r]), vlo);
            vhi = fmaf(a2, hi16(pk2f[k].u[r]), vhi);
            vlo = fmaf(a3, lo16(pk3[k].u[r]), vlo);
            vhi = fmaf(a3, hi16(pk3[k].u[r]), vhi);
            ob[(long)(k * 16 + 2 * r)     * THW] = vlo;
            ob[(long)(k * 16 + 2 * r + 1) * THW] = vhi;
        }

    // ---- alpha[b][s][thw] at offset B*F*THW; hi=0 -> s=0,1 ; hi=1 -> s=2,3
    float* ab = out + (long)NB * NF * THW + ((long)(b * NS + hi * 2)) * THW + thw;
    ab[0]   = hi ? a2 : a0;
    ab[THW] = hi ? a3 : a1;
}

extern "C" void kernel_launch(void* const* d_in, const int* in_sizes, int n_in,
                              void* d_out, int out_size, void* d_ws, size_t ws_size,
                              hipStream_t stream) {
    const float* feats = (const float*)d_in[0];
    const float* ps    = (const float*)d_in[1];
    const float* w1    = (const float*)d_in[2];
    const float* gamma = (const float*)d_in[3];
    const float* beta  = (const float*)d_in[4];
    const float* mean  = (const float*)d_in[5];
    const float* var   = (const float*)d_in[6];
    const float* w2    = (const float*)d_in[7];
    float* out = (float*)d_out;

    dim3 grid(2048), block(256);   // 2048 blocks x 128 px = 262144 pixels
    hipLaunchKernelGGL(gssm_kernel, grid, block, 0, stream,
                       feats, ps, w1, gamma, beta, mean, var, w2, out);
}

// Round 9
// 92.215 us; speedup vs baseline: 1.0407x; 1.0407x over previous
//
#include <hip/hip_runtime.h>
#include <hip/hip_bf16.h>
#include <stdint.h>

// Shapes (fixed): S=4, B=2, F=64, P=16, T=32, H=64, W=64, HID=32
#define THW   131072   // 32*64*64
#define NS    4
#define NB    2
#define NF    64
#define NP    16
#define HID   32
#define BN_EPS 1e-5f
#define PXT   128      // pixels per block tile (4 waves x 32-px MFMA tiles)

typedef short  bf16x8  __attribute__((ext_vector_type(8)));
typedef float  f32x16  __attribute__((ext_vector_type(16)));

union FragU { uint32_t u[4]; bf16x8 v; uint4 q; };

__device__ __forceinline__ uint32_t pk2(float a, float b) {
    __hip_bfloat162 h = __float22bfloat162_rn(make_float2(a, b));
    uint32_t r;
    __builtin_memcpy(&r, &h, sizeof(r));
    return r;
}
__device__ __forceinline__ float lo16(uint32_t u) { return __builtin_bit_cast(float, u << 16); }
__device__ __forceinline__ float hi16(uint32_t u) { return __builtin_bit_cast(float, u & 0xFFFF0000u); }

// async global->LDS, 16B/lane: wave writes lds_base + lane*16 (1KB contiguous),
// reads per-lane gsrc (must be 16B-stride-coherent with lane).
__device__ __forceinline__ void glds16(const float* g, void* l) {
    __builtin_amdgcn_global_load_lds(
        (const __attribute__((address_space(1))) uint32_t*)g,
        (__attribute__((address_space(3))) uint32_t*)l, 16, 0, 0);
}

// Block = 256 threads = 4 waves = 128 contiguous pixels; wave wv owns px wv*32..+31.
// R9 = R8 with the T4 counted-vmcnt schedule (never drain to 0 in the loop):
//   phase s: stage(s+1) -> vmcnt(8) [prev stage done, new 8 stay in flight]
//            -> barrier -> consume(s) -> barrier [buffer-reuse protection]
// R8's per-phase vmcnt(0) drained the CU's outstanding loads to zero at every
// barrier (sawtooth); this keeps 8 DMAs/wave in flight across consume.
__global__ __launch_bounds__(256, 2) void gssm_kernel(
    const float* __restrict__ feats, const float* __restrict__ ps,
    const float* __restrict__ w1,    const float* __restrict__ gamma,
    const float* __restrict__ beta,  const float* __restrict__ mean,
    const float* __restrict__ var,   const float* __restrict__ w2,
    float* __restrict__ out)
{
    __shared__ __align__(16) float    fbuf[2][NF][PXT];   // 65536 B
    __shared__ __align__(16) float    pbuf[NP][PXT];      //  8192 B
    __shared__ __align__(16) uint32_t w1lds[32 * 44];     //  5632 B
    __shared__ float2 tbl[HID];                           //   256 B

    const int tid  = threadIdx.x;
    const int lane = tid & 63;
    const int wv   = tid >> 6;
    const int hi   = lane >> 5;
    const int ln   = lane & 31;

    // ---- stage w1 (BN-scale folded, bf16-packed) + tbl
    for (int t = tid; t < 1280; t += 256) {
        float2 v = ((const float2*)w1)[t];
        int o = t / 40, cp = t - o * 40;
        float sc = gamma[o] * rsqrtf(var[o] + BN_EPS);
        w1lds[o * 44 + (cp >> 3) * 8 + (cp & 7)] = pk2(v.x * sc, v.y * sc);
    }
    if (tid < HID) {
        float sc = gamma[tid] * rsqrtf(var[tid] + BN_EPS);
        tbl[tid] = make_float2(beta[tid] - mean[tid] * sc, w2[tid]);
    }

    const int px0g = blockIdx.x * PXT;        // global pixel (incl. b)
    const int b    = px0g >> 17;              // THW = 2^17
    const int px0  = px0g & (THW - 1);

    const float* featsb = feats + (long)b * NF * THW + px0;
    const float* psb    = ps    + (long)b * NP * THW + px0;
    const long   sstr   = (long)NB * NF * THW;

    // per-lane src offset within a plane-PAIR: lanes 0-31 -> plane f, px 4*ln..;
    // lanes 32-63 -> plane f+1. Matches LDS dest base+lane*16 over [f][128],[f+1][128].
    const long pl_off = (long)(lane >> 5) * THW + (ln << 2);
    const int  f0     = wv * 16;              // wave stages planes f0..f0+15 (8 instrs)

    auto stage_feats = [&](int s, int buf) {
        const float* base = featsb + (long)s * sstr;
        #pragma unroll
        for (int i = 0; i < 8; ++i) {
            int f = f0 + i * 2;
            glds16(base + (long)f * THW + pl_off, (void*)&fbuf[buf][f][0]);
        }
    };

    // ---- prologue: stage p (16 planes = 8 instrs, 2/wave) + feats(s=0)
    {
        #pragma unroll
        for (int i = 0; i < 2; ++i) {
            int p = wv * 4 + i * 2;
            glds16(psb + (long)p * THW + pl_off, (void*)&pbuf[p][0]);
        }
    }
    stage_feats(0, 0);
    asm volatile("s_waitcnt vmcnt(0) lgkmcnt(0)" ::: "memory");
    __builtin_amdgcn_s_barrier();

    // ---- hoist A fragments (w1*scale) and shift/w2
    FragU afr[5];
    {
        const uint32_t abase = (uint32_t)(ln * 44 + hi * 4);
        #pragma unroll
        for (int k = 0; k < 5; ++k)
            afr[k].q = *((const uint4*)&w1lds[abase + k * 8]);
    }
    float sh[16], wo[16];
    #pragma unroll
    for (int r = 0; r < 16; ++r) {
        float2 t = tbl[(r & 3) + 8 * (r >> 2) + 4 * hi];
        sh[r] = t.x;
        wo[r] = t.y;
    }

    const int pxloc = wv * 32 + ln;           // this lane's pixel within the block tile

    // ---- p fragment from pbuf (once)
    FragU bp;
    #pragma unroll
    for (int r = 0; r < 4; ++r)
        bp.u[r] = pk2(pbuf[hi * 8 + 2 * r][pxloc], pbuf[hi * 8 + 2 * r + 1][pxloc]);

    auto consume = [&](int buf, FragU* pk) -> float {
        #pragma unroll
        for (int kb = 0; kb < 4; ++kb)
            #pragma unroll
            for (int r = 0; r < 4; ++r)
                pk[kb].u[r] = pk2(fbuf[buf][kb * 16 + hi * 8 + 2 * r][pxloc],
                                  fbuf[buf][kb * 16 + hi * 8 + 2 * r + 1][pxloc]);
        f32x16 acc;
        #pragma unroll
        for (int r = 0; r < 16; ++r) acc[r] = 0.f;
        acc = __builtin_amdgcn_mfma_f32_32x32x16_bf16(afr[4].v, bp.v,    acc, 0, 0, 0);
        acc = __builtin_amdgcn_mfma_f32_32x32x16_bf16(afr[0].v, pk[0].v, acc, 0, 0, 0);
        acc = __builtin_amdgcn_mfma_f32_32x32x16_bf16(afr[1].v, pk[1].v, acc, 0, 0, 0);
        acc = __builtin_amdgcn_mfma_f32_32x32x16_bf16(afr[2].v, pk[2].v, acc, 0, 0, 0);
        acc = __builtin_amdgcn_mfma_f32_32x32x16_bf16(afr[3].v, pk[3].v, acc, 0, 0, 0);
        float pp[4] = {0.f, 0.f, 0.f, 0.f};
        #pragma unroll
        for (int r = 0; r < 16; ++r) {
            float h = fmaxf(acc[r] + sh[r], 0.f);
            pp[r & 3] = fmaf(h, wo[r], pp[r & 3]);
        }
        float part = (pp[0] + pp[1]) + (pp[2] + pp[3]);
        return part + __shfl_xor(part, 32);
    };

    FragU pk0[4], pk1[4], pk2f[4], pk3[4];
    float lg0, lg1, lg2, lg3;

    // ---- phase 0: stage(1) flies through consume(0)
    stage_feats(1, 1);
    asm volatile("s_waitcnt vmcnt(8)" ::: "memory");   // no-op (b0 ready from prologue)
    __builtin_amdgcn_s_barrier();
    lg0 = consume(0, pk0);
    __builtin_amdgcn_s_barrier();                      // all waves done with b0

    // ---- phase 1
    stage_feats(2, 0);
    asm volatile("s_waitcnt vmcnt(8)" ::: "memory");   // stage(1) done; stage(2) in flight
    __builtin_amdgcn_s_barrier();
    lg1 = consume(1, pk1);
    __builtin_amdgcn_s_barrier();

    // ---- phase 2
    stage_feats(3, 1);
    asm volatile("s_waitcnt vmcnt(8)" ::: "memory");   // stage(2) done; stage(3) in flight
    __builtin_amdgcn_s_barrier();
    lg2 = consume(0, pk2f);
    __builtin_amdgcn_s_barrier();

    // ---- phase 3 (only full drain in the loop)
    asm volatile("s_waitcnt vmcnt(0)" ::: "memory");   // stage(3) done
    __builtin_amdgcn_s_barrier();
    lg3 = consume(1, pk3);

    // ---- softmax over 4 logits (b2 shift-invariant: skipped)
    const float m   = fmaxf(fmaxf(lg0, lg1), fmaxf(lg2, lg3));
    const float e0  = __expf(lg0 - m), e1 = __expf(lg1 - m);
    const float e2  = __expf(lg2 - m), e3 = __expf(lg3 - m);
    const float inv = 1.f / (e0 + e1 + e2 + e3);
    const float a0 = e0 * inv, a1 = e1 * inv, a2 = e2 * inv, a3 = e3 * inv;

    const int thw = px0 + pxloc;

    // ---- out[b][f][thw] = sum_s alpha_s * feats_s (from bf16 frags), f = k*16+hi*8+j
    float* ob = out + ((long)(b * NF + hi * 8)) * THW + thw;
    #pragma unroll
    for (int k = 0; k < 4; ++k)
        #pragma unroll
        for (int r = 0; r < 4; ++r) {
            float vlo = a0 * lo16(pk0[k].u[r]);
            float vhi = a0 * hi16(pk0[k].u[r]);
            vlo = fmaf(a1, lo16(pk1[k].u[r]), vlo);
            vhi = fmaf(a1, hi16(pk1[k].u[r]), vhi);
            vlo = fmaf(a2, lo16(pk2f[k].u[r]), vlo);
            vhi = fmaf(a2, hi16(pk2f[k].u[r]), vhi);
            vlo = fmaf(a3, lo16(pk3[k].u[r]), vlo);
            vhi = fmaf(a3, hi16(pk3[k].u[r]), vhi);
            ob[(long)(k * 16 + 2 * r)     * THW] = vlo;
            ob[(long)(k * 16 + 2 * r + 1) * THW] = vhi;
        }

    // ---- alpha[b][s][thw] at offset B*F*THW; hi=0 -> s=0,1 ; hi=1 -> s=2,3
    float* ab = out + (long)NB * NF * THW + ((long)(b * NS + hi * 2)) * THW + thw;
    ab[0]   = hi ? a2 : a0;
    ab[THW] = hi ? a3 : a1;
}

extern "C" void kernel_launch(void* const* d_in, const int* in_sizes, int n_in,
                              void* d_out, int out_size, void* d_ws, size_t ws_size,
                              hipStream_t stream) {
    const float* feats = (const float*)d_in[0];
    const float* ps    = (const float*)d_in[1];
    const float* w1    = (const float*)d_in[2];
    const float* gamma = (const float*)d_in[3];
    const float* beta  = (const float*)d_in[4];
    const float* mean  = (const float*)d_in[5];
    const float* var   = (const float*)d_in[6];
    const float* w2    = (const float*)d_in[7];
    float* out = (float*)d_out;

    dim3 grid(2048), block(256);   // 2048 blocks x 128 px = 262144 pixels
    hipLaunchKernelGGL(gssm_kernel, grid, block, 0, stream,
                       feats, ps, w1, gamma, beta, mean, var, w2, out);
}

// Round 10
// 84.068 us; speedup vs baseline: 1.1415x; 1.0969x over previous
//
#include <hip/hip_runtime.h>
#include <hip/hip_bf16.h>
#include <stdint.h>

// Shapes (fixed): S=4, B=2, F=64, P=16, T=32, H=64, W=64, HID=32
#define THW   131072   // 32*64*64
#define NS    4
#define NB    2
#define NF    64
#define NP    16
#define HID   32
#define BN_EPS 1e-5f
#define PXT   128      // pixels per block tile (4 waves x 32-px MFMA tiles)

typedef short  bf16x8  __attribute__((ext_vector_type(8)));
typedef float  f32x16  __attribute__((ext_vector_type(16)));

union FragU { uint32_t u[4]; bf16x8 v; uint4 q; };

__device__ __forceinline__ uint32_t pk2(float a, float b) {
    __hip_bfloat162 h = __float22bfloat162_rn(make_float2(a, b));
    uint32_t r;
    __builtin_memcpy(&r, &h, sizeof(r));
    return r;
}
__device__ __forceinline__ float lo16(uint32_t u) { return __builtin_bit_cast(float, u << 16); }
__device__ __forceinline__ float hi16(uint32_t u) { return __builtin_bit_cast(float, u & 0xFFFF0000u); }

// async global->LDS, 16B/lane: wave writes lds_base + lane*16 (1KB contiguous),
// reads per-lane gsrc (must be 16B-stride-coherent with lane).
__device__ __forceinline__ void glds16(const float* g, void* l) {
    __builtin_amdgcn_global_load_lds(
        (const __attribute__((address_space(1))) uint32_t*)g,
        (__attribute__((address_space(3))) uint32_t*)l, 16, 0, 0);
}

// R10 = R9 + bit-reversed block->tile swizzle.
// All plane strides are exactly 512KB (power of 2); consecutive blockIdx tiles
// are 512B apart, so the ~512 resident blocks cover only ~half the HBM channel
// positions at any instant (R1..R9 all pinned at 3.8-3.9 TB/s regardless of
// structure). brev11 spreads the resident cohort uniformly every 4 tiles across
// the full 512KB px0 space -> all channel positions covered.
__global__ __launch_bounds__(256, 2) void gssm_kernel(
    const float* __restrict__ feats, const float* __restrict__ ps,
    const float* __restrict__ w1,    const float* __restrict__ gamma,
    const float* __restrict__ beta,  const float* __restrict__ mean,
    const float* __restrict__ var,   const float* __restrict__ w2,
    float* __restrict__ out)
{
    __shared__ __align__(16) float    fbuf[2][NF][PXT];   // 65536 B
    __shared__ __align__(16) float    pbuf[NP][PXT];      //  8192 B
    __shared__ __align__(16) uint32_t w1lds[32 * 44];     //  5632 B
    __shared__ float2 tbl[HID];                           //   256 B

    const int tid  = threadIdx.x;
    const int lane = tid & 63;
    const int wv   = tid >> 6;
    const int hi   = lane >> 5;
    const int ln   = lane & 31;

    // ---- stage w1 (BN-scale folded, bf16-packed) + tbl
    for (int t = tid; t < 1280; t += 256) {
        float2 v = ((const float2*)w1)[t];
        int o = t / 40, cp = t - o * 40;
        float sc = gamma[o] * rsqrtf(var[o] + BN_EPS);
        w1lds[o * 44 + (cp >> 3) * 8 + (cp & 7)] = pk2(v.x * sc, v.y * sc);
    }
    if (tid < HID) {
        float sc = gamma[tid] * rsqrtf(var[tid] + BN_EPS);
        tbl[tid] = make_float2(beta[tid] - mean[tid] * sc, w2[tid]);
    }

    const int tile = (int)(__brev((unsigned)blockIdx.x) >> 21);  // 11-bit bitrev, 2048 tiles
    const int px0g = tile * PXT;              // global pixel (incl. b)
    const int b    = px0g >> 17;              // THW = 2^17
    const int px0  = px0g & (THW - 1);

    const float* featsb = feats + (long)b * NF * THW + px0;
    const float* psb    = ps    + (long)b * NP * THW + px0;
    const long   sstr   = (long)NB * NF * THW;

    // per-lane src offset within a plane-PAIR: lanes 0-31 -> plane f, px 4*ln..;
    // lanes 32-63 -> plane f+1. Matches LDS dest base+lane*16 over [f][128],[f+1][128].
    const long pl_off = (long)(lane >> 5) * THW + (ln << 2);
    const int  f0     = wv * 16;              // wave stages planes f0..f0+15 (8 instrs)

    auto stage_feats = [&](int s, int buf) {
        const float* base = featsb + (long)s * sstr;
        #pragma unroll
        for (int i = 0; i < 8; ++i) {
            int f = f0 + i * 2;
            glds16(base + (long)f * THW + pl_off, (void*)&fbuf[buf][f][0]);
        }
    };

    // ---- prologue: stage p (16 planes = 8 instrs, 2/wave) + feats(s=0)
    {
        #pragma unroll
        for (int i = 0; i < 2; ++i) {
            int p = wv * 4 + i * 2;
            glds16(psb + (long)p * THW + pl_off, (void*)&pbuf[p][0]);
        }
    }
    stage_feats(0, 0);
    asm volatile("s_waitcnt vmcnt(0) lgkmcnt(0)" ::: "memory");
    __builtin_amdgcn_s_barrier();

    // ---- hoist A fragments (w1*scale) and shift/w2
    FragU afr[5];
    {
        const uint32_t abase = (uint32_t)(ln * 44 + hi * 4);
        #pragma unroll
        for (int k = 0; k < 5; ++k)
            afr[k].q = *((const uint4*)&w1lds[abase + k * 8]);
    }
    float sh[16], wo[16];
    #pragma unroll
    for (int r = 0; r < 16; ++r) {
        float2 t = tbl[(r & 3) + 8 * (r >> 2) + 4 * hi];
        sh[r] = t.x;
        wo[r] = t.y;
    }

    const int pxloc = wv * 32 + ln;           // this lane's pixel within the block tile

    // ---- p fragment from pbuf (once)
    FragU bp;
    #pragma unroll
    for (int r = 0; r < 4; ++r)
        bp.u[r] = pk2(pbuf[hi * 8 + 2 * r][pxloc], pbuf[hi * 8 + 2 * r + 1][pxloc]);

    auto consume = [&](int buf, FragU* pk) -> float {
        #pragma unroll
        for (int kb = 0; kb < 4; ++kb)
            #pragma unroll
            for (int r = 0; r < 4; ++r)
                pk[kb].u[r] = pk2(fbuf[buf][kb * 16 + hi * 8 + 2 * r][pxloc],
                                  fbuf[buf][kb * 16 + hi * 8 + 2 * r + 1][pxloc]);
        f32x16 acc;
        #pragma unroll
        for (int r = 0; r < 16; ++r) acc[r] = 0.f;
        acc = __builtin_amdgcn_mfma_f32_32x32x16_bf16(afr[4].v, bp.v,    acc, 0, 0, 0);
        acc = __builtin_amdgcn_mfma_f32_32x32x16_bf16(afr[0].v, pk[0].v, acc, 0, 0, 0);
        acc = __builtin_amdgcn_mfma_f32_32x32x16_bf16(afr[1].v, pk[1].v, acc, 0, 0, 0);
        acc = __builtin_amdgcn_mfma_f32_32x32x16_bf16(afr[2].v, pk[2].v, acc, 0, 0, 0);
        acc = __builtin_amdgcn_mfma_f32_32x32x16_bf16(afr[3].v, pk[3].v, acc, 0, 0, 0);
        float pp[4] = {0.f, 0.f, 0.f, 0.f};
        #pragma unroll
        for (int r = 0; r < 16; ++r) {
            float h = fmaxf(acc[r] + sh[r], 0.f);
            pp[r & 3] = fmaf(h, wo[r], pp[r & 3]);
        }
        float part = (pp[0] + pp[1]) + (pp[2] + pp[3]);
        return part + __shfl_xor(part, 32);
    };

    FragU pk0[4], pk1[4], pk2f[4], pk3[4];
    float lg0, lg1, lg2, lg3;

    // ---- phase 0: stage(1) flies through consume(0)
    stage_feats(1, 1);
    asm volatile("s_waitcnt vmcnt(8)" ::: "memory");   // no-op (b0 ready from prologue)
    __builtin_amdgcn_s_barrier();
    lg0 = consume(0, pk0);
    __builtin_amdgcn_s_barrier();                      // all waves done with b0

    // ---- phase 1
    stage_feats(2, 0);
    asm volatile("s_waitcnt vmcnt(8)" ::: "memory");   // stage(1) done; stage(2) in flight
    __builtin_amdgcn_s_barrier();
    lg1 = consume(1, pk1);
    __builtin_amdgcn_s_barrier();

    // ---- phase 2
    stage_feats(3, 1);
    asm volatile("s_waitcnt vmcnt(8)" ::: "memory");   // stage(2) done; stage(3) in flight
    __builtin_amdgcn_s_barrier();
    lg2 = consume(0, pk2f);
    __builtin_amdgcn_s_barrier();

    // ---- phase 3 (only full drain in the loop)
    asm volatile("s_waitcnt vmcnt(0)" ::: "memory");   // stage(3) done
    __builtin_amdgcn_s_barrier();
    lg3 = consume(1, pk3);

    // ---- softmax over 4 logits (b2 shift-invariant: skipped)
    const float m   = fmaxf(fmaxf(lg0, lg1), fmaxf(lg2, lg3));
    const float e0  = __expf(lg0 - m), e1 = __expf(lg1 - m);
    const float e2  = __expf(lg2 - m), e3 = __expf(lg3 - m);
    const float inv = 1.f / (e0 + e1 + e2 + e3);
    const float a0 = e0 * inv, a1 = e1 * inv, a2 = e2 * inv, a3 = e3 * inv;

    const int thw = px0 + pxloc;

    // ---- out[b][f][thw] = sum_s alpha_s * feats_s (from bf16 frags), f = k*16+hi*8+j
    float* ob = out + ((long)(b * NF + hi * 8)) * THW + thw;
    #pragma unroll
    for (int k = 0; k < 4; ++k)
        #pragma unroll
        for (int r = 0; r < 4; ++r) {
            float vlo = a0 * lo16(pk0[k].u[r]);
            float vhi = a0 * hi16(pk0[k].u[r]);
            vlo = fmaf(a1, lo16(pk1[k].u[r]), vlo);
            vhi = fmaf(a1, hi16(pk1[k].u[r]), vhi);
            vlo = fmaf(a2, lo16(pk2f[k].u[r]), vlo);
            vhi = fmaf(a2, hi16(pk2f[k].u[r]), vhi);
            vlo = fmaf(a3, lo16(pk3[k].u[r]), vlo);
            vhi = fmaf(a3, hi16(pk3[k].u[r]), vhi);
            ob[(long)(k * 16 + 2 * r)     * THW] = vlo;
            ob[(long)(k * 16 + 2 * r + 1) * THW] = vhi;
        }

    // ---- alpha[b][s][thw] at offset B*F*THW; hi=0 -> s=0,1 ; hi=1 -> s=2,3
    float* ab = out + (long)NB * NF * THW + ((long)(b * NS + hi * 2)) * THW + thw;
    ab[0]   = hi ? a2 : a0;
    ab[THW] = hi ? a3 : a1;
}

extern "C" void kernel_launch(void* const* d_in, const int* in_sizes, int n_in,
                              void* d_out, int out_size, void* d_ws, size_t ws_size,
                              hipStream_t stream) {
    const float* feats = (const float*)d_in[0];
    const float* ps    = (const float*)d_in[1];
    const float* w1    = (const float*)d_in[2];
    const float* gamma = (const float*)d_in[3];
    const float* beta  = (const float*)d_in[4];
    const float* mean  = (const float*)d_in[5];
    const float* var   = (const float*)d_in[6];
    const float* w2    = (const float*)d_in[7];
    float* out = (float*)d_out;

    dim3 grid(2048), block(256);   // 2048 blocks x 128 px = 262144 pixels
    hipLaunchKernelGGL(gssm_kernel, grid, block, 0, stream,
                       feats, ps, w1, gamma, beta, mean, var, w2, out);
}